// Round 3
// baseline (5413.465 us; speedup 1.0000x reference)
//
#include <hip/hip_runtime.h>
#include <stdint.h>
#include <math.h>
#include <algorithm>

#define NS 8
#define NA 1024
#define NK 5
#define MAXIT 30
#define TOLER 1e-5

// ---------------- host-side threefry-2x32 (JAX-compatible) ----------------
static inline void tf2x32(uint32_t k0, uint32_t k1, uint32_t c0, uint32_t c1,
                          uint32_t& o0, uint32_t& o1) {
  uint32_t ks2 = k0 ^ k1 ^ 0x1BD11BDAu;
  uint32_t x0 = c0 + k0, x1 = c1 + k1;
  auto rot = [](uint32_t x, int r) { return (x << r) | (x >> (32 - r)); };
  auto R4 = [&](int r0, int r1, int r2, int r3) {
    x0 += x1; x1 = rot(x1, r0); x1 ^= x0;
    x0 += x1; x1 = rot(x1, r1); x1 ^= x0;
    x0 += x1; x1 = rot(x1, r2); x1 ^= x0;
    x0 += x1; x1 = rot(x1, r3); x1 ^= x0;
  };
  R4(13, 15, 26, 6);  x0 += k1;  x1 += ks2 + 1u;
  R4(17, 29, 16, 24); x0 += ks2; x1 += k0 + 2u;
  R4(13, 15, 26, 6);  x0 += k0;  x1 += k1 + 3u;
  R4(17, 29, 16, 24); x0 += k1;  x1 += ks2 + 4u;
  R4(13, 15, 26, 6);  x0 += ks2; x1 += k0 + 5u;
  o0 = x0; o1 = x1;
}

struct InitIdx { int v[NS * NK]; };

// jax_threefry_partitionable=True (default since JAX 0.4.36) semantics:
//   split(key,(n,)):  keys[s] = tf(key, ctr=(0,s))            [iota_2x32 hi/lo]
//   random_bits(key,32,(n,)): bits[i] = o0^o1 of tf(key,(0,i))
// choice(key,1024,(5,),replace=False) == _shuffle (1 sort round):
//   subkey = split(key)[1] = tf(key,(0,1)); argsort_stable(bits)[:5]
static void compute_init_indices(InitIdx& out) {
  const uint32_t rk0 = 0, rk1 = 42;  // jax.random.key(42) -> (0,42)
  for (int s = 0; s < NS; s++) {
    uint32_t k0, k1;
    tf2x32(rk0, rk1, 0u, (uint32_t)s, k0, k1);   // keys[s]
    uint32_t sk0, sk1;
    tf2x32(k0, k1, 0u, 1u, sk0, sk1);            // subkey = split(key)[1]
    uint32_t bits[NA];
    for (int i = 0; i < NA; i++) {
      uint32_t b0, b1;
      tf2x32(sk0, sk1, 0u, (uint32_t)i, b0, b1);
      bits[i] = b0 ^ b1;                          // 32-bit partitionable bits
    }
    int idx[NA];
    for (int i = 0; i < NA; i++) idx[i] = i;
    std::stable_sort(idx, idx + NA, [&](int x, int y) { return bits[x] < bits[y]; });
    for (int c = 0; c < NK; c++) out.v[s * NK + c] = idx[c];
  }
}

// ---------------- device helpers ----------------
__device__ __forceinline__ double blk_reduce256(double v, double* red) {
  int t = threadIdx.x;
  red[t] = v;
  __syncthreads();
#pragma unroll
  for (int off = 128; off > 0; off >>= 1) {
    if (t < off) red[t] += red[t + off];
    __syncthreads();
  }
  double r = red[0];
  __syncthreads();
  return r;
}

__device__ __forceinline__ double wave_reduce64(double v) {
#pragma unroll
  for (int m = 32; m > 0; m >>= 1) v += __shfl_xor(v, m, 64);
  return v;
}

// ---------------- kernels (all f64 state; cov stays the given f32) ----------------
__global__ __launch_bounds__(256) void k_rstd(const float* __restrict__ cov, double* __restrict__ rstd) {
  int gid = blockIdx.x * 256 + threadIdx.x;
  if (gid >= NS * NA) return;
  int s = gid >> 10, a = gid & 1023;
  double d = (double)cov[(size_t)s * NA * NA + (size_t)a * NA + a];
  rstd[gid] = 1.0 / sqrt(d);
}

__global__ __launch_bounds__(256) void k_xn(const float* __restrict__ cov, const double* __restrict__ rstd,
                                            double* __restrict__ xn) {
  int w = blockIdx.x;  // 512 = 8 samples x 64 blocks x 16 rows
  int s = w >> 6;
  __shared__ double rsh[NA];
  for (int j = threadIdx.x; j < NA; j += 256) rsh[j] = rstd[s * NA + j];
  __syncthreads();
  int lane = threadIdx.x & 63, wave = threadIdx.x >> 6;
  const float* covS = cov + (size_t)s * NA * NA;
  for (int q = 0; q < 4; q++) {
    int i = (w & 63) * 16 + wave * 4 + q;
    const float* row = covS + (size_t)i * NA;
    double acc = 0.0;
    for (int j = lane; j < NA; j += 64) {
      double v = (double)row[j] * rsh[j];
      acc += v * v;
    }
    acc = wave_reduce64(acc);
    if (lane == 0) {
      double ri = rsh[i];
      xn[s * NA + i] = acc * ri * ri;
    }
  }
}

__global__ __launch_bounds__(256) void k_centers_init(const float* __restrict__ cov, const double* __restrict__ rstd,
                                                      double* __restrict__ C, InitIdx ii) {
  int w = blockIdx.x;  // 40
  int s = w / NK, k = w % NK;
  int idx = ii.v[s * NK + k];
  const float* row = cov + (size_t)s * NA * NA + (size_t)idx * NA;
  const double* rs = rstd + s * NA;
  double ri = rs[idx];
  for (int j = threadIdx.x; j < NA; j += 256)
    C[((size_t)s * NK + k) * NA + j] = (double)row[j] * ri * rs[j];
}

__global__ void k_state_init(double* pot, int* conv) {
  int t = threadIdx.x;
  if (t < NS) { pot[t] = INFINITY; conv[t] = 0; }
}

__global__ __launch_bounds__(256) void k_assign(const float* __restrict__ cov, const double* __restrict__ rstd,
                                                const double* __restrict__ xn, const double* __restrict__ C,
                                                const int* __restrict__ conv, int* __restrict__ ixs,
                                                double* __restrict__ mind) {
  int w = blockIdx.x;  // 512
  int s = w >> 6;
  if (conv[s]) return;
  __shared__ double Cs[NK][NA];  // rstd_j-scaled centers (40 KB)
  __shared__ double red[256];
  __shared__ double cn[NK];
  const double* rs = rstd + s * NA;
  double sq[NK] = {0, 0, 0, 0, 0};
  for (int k = 0; k < NK; k++) {
    for (int j = threadIdx.x; j < NA; j += 256) {
      double c = C[((size_t)s * NK + k) * NA + j];
      sq[k] += c * c;
      Cs[k][j] = c * rs[j];
    }
  }
  __syncthreads();
  for (int k = 0; k < NK; k++) {
    double tk = blk_reduce256(sq[k], red);
    if (threadIdx.x == 0) cn[k] = tk;
  }
  __syncthreads();
  int lane = threadIdx.x & 63, wave = threadIdx.x >> 6;
  const float* covS = cov + (size_t)s * NA * NA;
  for (int q = 0; q < 4; q++) {
    int i = (w & 63) * 16 + wave * 4 + q;
    const float* row = covS + (size_t)i * NA;
    double a0 = 0, a1 = 0, a2 = 0, a3 = 0, a4 = 0;
    for (int j = lane; j < NA; j += 64) {
      double cv = (double)row[j];
      a0 += cv * Cs[0][j];
      a1 += cv * Cs[1][j];
      a2 += cv * Cs[2][j];
      a3 += cv * Cs[3][j];
      a4 += cv * Cs[4][j];
    }
    a0 = wave_reduce64(a0); a1 = wave_reduce64(a1); a2 = wave_reduce64(a2);
    a3 = wave_reduce64(a3); a4 = wave_reduce64(a4);
    if (lane == 0) {
      double xi = xn[s * NA + i];
      double ri = rs[i];
      double dots[5] = {a0, a1, a2, a3, a4};
      double best = INFINITY;
      int bk = 0;
#pragma unroll
      for (int k = 0; k < NK; k++) {
        double d = xi + cn[k] - 2.0 * ri * dots[k];
        if (d < 0.0) d = 0.0;
        if (d < best) { best = d; bk = k; }  // strict < : first-min like jnp.argmin
      }
      ixs[s * NA + i] = bk;
      mind[s * NA + i] = best;
    }
  }
}

__global__ __launch_bounds__(256) void k_update(const float* __restrict__ cov, const double* __restrict__ rstd,
                                                const int* __restrict__ ixs, const double* __restrict__ mind,
                                                double* __restrict__ C, double* __restrict__ pot,
                                                int* __restrict__ conv) {
  int w = blockIdx.x;  // 32 center blocks (s x 4 segs, all 5 clusters fused) + 8 pot blocks
  int t = threadIdx.x;
  __shared__ int ixsh[NA];
  __shared__ double rssh[NA];
  __shared__ double red[256];
  if (w < 32) {
    int s = w >> 2, seg = w & 3;
    if (conv[s]) return;
    for (int i = t; i < NA; i += 256) { ixsh[i] = ixs[s * NA + i]; rssh[i] = rstd[s * NA + i]; }
    __syncthreads();
    int j = seg * 256 + t;
    const float* covS = cov + (size_t)s * NA * NA;
    double a0 = 0, a1 = 0, a2 = 0, a3 = 0, a4 = 0;
    int c0 = 0, c1 = 0, c2 = 0, c3 = 0, c4 = 0;
    for (int i = 0; i < NA; i++) {  // fixed ascending order: deterministic
      int kk = ixsh[i];
      double v = rssh[i] * (double)covS[(size_t)i * NA + j];
      a0 += (kk == 0) ? v : 0.0; c0 += (kk == 0);
      a1 += (kk == 1) ? v : 0.0; c1 += (kk == 1);
      a2 += (kk == 2) ? v : 0.0; c2 += (kk == 2);
      a3 += (kk == 3) ? v : 0.0; c3 += (kk == 3);
      a4 += (kk == 4) ? v : 0.0; c4 += (kk == 4);
    }
    double rj = rssh[j];
    double* CS = C + (size_t)s * NK * NA;
    if (c0 > 0) CS[0 * NA + j] = a0 * rj / (double)c0;
    if (c1 > 0) CS[1 * NA + j] = a1 * rj / (double)c1;
    if (c2 > 0) CS[2 * NA + j] = a2 * rj / (double)c2;
    if (c3 > 0) CS[3 * NA + j] = a3 * rj / (double)c3;
    if (c4 > 0) CS[4 * NA + j] = a4 * rj / (double)c4;
    // empty cluster: keep previous center (matches jnp.where(counts>0,...))
  } else {
    int s = w - 32;
    if (conv[s]) return;
    double v = mind[s * NA + t] + mind[s * NA + 256 + t] +
               mind[s * NA + 512 + t] + mind[s * NA + 768 + t];
    double p = blk_reduce256(v, red);
    if (t == 0) {
      double prev = pot[s];
      pot[s] = p;
      if (!(fabs(p - prev) >= TOLER)) conv[s] = 1;  // while-cond fails -> freeze sample
    }
  }
}

__global__ __launch_bounds__(256) void k_members(const int* __restrict__ ixs, int* __restrict__ g,
                                                 int* __restrict__ cnt, int* __restrict__ off5) {
  int s = blockIdx.x, t = threadIdx.x;
  __shared__ int sc[NK][256];
  __shared__ int base[NK];
  const int* ix = ixs + s * NA;
  int my[4];
  int lc[NK] = {0, 0, 0, 0, 0};
#pragma unroll
  for (int q = 0; q < 4; q++) { my[q] = ix[t * 4 + q]; lc[my[q]]++; }
#pragma unroll
  for (int k = 0; k < NK; k++) sc[k][t] = lc[k];
  __syncthreads();
  for (int off = 1; off < 256; off <<= 1) {
    int v[NK];
#pragma unroll
    for (int k = 0; k < NK; k++) v[k] = (t >= off) ? sc[k][t - off] : 0;
    __syncthreads();
#pragma unroll
    for (int k = 0; k < NK; k++) sc[k][t] += v[k];
    __syncthreads();
  }
  if (t == 0) {
    int b = 0;
    for (int k = 0; k < NK; k++) {
      int tot = sc[k][255];
      base[k] = b;
      cnt[s * NK + k] = tot;
      off5[s * NK + k] = b;
      b += tot;
    }
  }
  __syncthreads();
  int pos[NK];
#pragma unroll
  for (int k = 0; k < NK; k++) pos[k] = base[k] + sc[k][t] - lc[k];
#pragma unroll
  for (int q = 0; q < 4; q++) {
    int k = my[q];
    int p = pos[k]++;
    g[s * NA + p] = t * 4 + q;  // stable: ascending asset index within cluster
  }
}

// f64 CG on the gathered diagonal block: Sigma_cc x = 1, normalize, scatter to original order.
__global__ __launch_bounds__(256) void k_cg(const float* __restrict__ cov, const int* __restrict__ g,
                                            const int* __restrict__ cnt, const int* __restrict__ off5,
                                            double* __restrict__ walloc) {
  int w = blockIdx.x;  // 40
  int s = w / NK, k = w % NK;
  int n = cnt[s * NK + k];
  if (n == 0) return;
  int off = off5[s * NK + k];
  const float* covS = cov + (size_t)s * NA * NA;
  __shared__ int gs[NA];
  __shared__ double xv[NA], rv[NA], pv[NA], ap[NA];
  __shared__ double red[256];
  int t = threadIdx.x, lane = t & 63, wave = t >> 6;
  for (int i = t; i < n; i += 256) {
    gs[i] = g[s * NA + off + i];
    xv[i] = 0.0; rv[i] = 1.0; pv[i] = 1.0;
  }
  double rr = (double)n;
  __syncthreads();
  for (int iter = 0; iter < 200; iter++) {
    for (int i = wave; i < n; i += 4) {  // wave-per-row matvec, gathered columns
      const float* Ar = covS + (size_t)gs[i] * NA;
      double a = 0.0;
      for (int j = lane; j < n; j += 64) a += (double)Ar[gs[j]] * pv[j];
      a = wave_reduce64(a);
      if (lane == 0) ap[i] = a;
    }
    __syncthreads();
    double pap_p = 0.0;
    for (int i = t; i < n; i += 256) pap_p += pv[i] * ap[i];
    double pap = blk_reduce256(pap_p, red);
    double alpha = rr / pap;
    double rrn_p = 0.0;
    for (int i = t; i < n; i += 256) {
      xv[i] += alpha * pv[i];
      double rn = rv[i] - alpha * ap[i];
      rv[i] = rn;
      rrn_p += rn * rn;
    }
    double rrn = blk_reduce256(rrn_p, red);
    if (rrn < 1e-22 * (double)n || iter == 199) break;
    double beta = rrn / rr;
    rr = rrn;
    for (int i = t; i < n; i += 256) pv[i] = rv[i] + beta * pv[i];
    __syncthreads();
  }
  double dp = 0.0;
  for (int i = t; i < n; i += 256) dp += xv[i];
  double denom = blk_reduce256(dp, red);
  for (int i = t; i < n; i += 256) walloc[s * NA + gs[i]] = xv[i] / denom;
}

// y2[s][k][j] = sum_{i in cluster k} w_i * cov[i][j]  (j in ORIGINAL order, coalesced)
__global__ __launch_bounds__(256) void k_intery(const float* __restrict__ cov, const double* __restrict__ walloc,
                                                const int* __restrict__ g, const int* __restrict__ cnt,
                                                const int* __restrict__ off5, double* __restrict__ y2) {
  int w = blockIdx.x;  // 160 = 8 x 5 x 4 segs
  int s = w / 20, rem = w % 20, k = rem / 4, seg = rem % 4;
  int n = cnt[s * NK + k], off = off5[s * NK + k];
  int t = threadIdx.x;
  __shared__ int gsl[NA];
  __shared__ double wl[NA];
  for (int i = t; i < n; i += 256) {
    int a = g[s * NA + off + i];
    gsl[i] = a;
    wl[i] = walloc[s * NA + a];
  }
  __syncthreads();
  int j = seg * 256 + t;
  const float* covS = cov + (size_t)s * NA * NA;
  double acc = 0.0;
  for (int i = 0; i < n; i++) acc += wl[i] * (double)covS[(size_t)gsl[i] * NA + j];
  y2[((size_t)s * NK + k) * NA + j] = acc;
}

__global__ __launch_bounds__(256) void k_icov(const double* __restrict__ y2, const double* __restrict__ walloc,
                                              const int* __restrict__ ixs, double* __restrict__ w_inter) {
  int s = blockIdx.x, t = threadIdx.x;
  __shared__ double red[256];
  __shared__ double ic[NK * NK];
  for (int k = 0; k < NK; k++) {
    double p0 = 0, p1 = 0, p2 = 0, p3 = 0, p4 = 0;
    for (int j = t; j < NA; j += 256) {
      double v = y2[((size_t)s * NK + k) * NA + j] * walloc[s * NA + j];
      int c = ixs[s * NA + j];
      p0 += (c == 0) ? v : 0.0;
      p1 += (c == 1) ? v : 0.0;
      p2 += (c == 2) ? v : 0.0;
      p3 += (c == 3) ? v : 0.0;
      p4 += (c == 4) ? v : 0.0;
    }
    double q0 = blk_reduce256(p0, red);
    double q1 = blk_reduce256(p1, red);
    double q2 = blk_reduce256(p2, red);
    double q3 = blk_reduce256(p3, red);
    double q4 = blk_reduce256(p4, red);
    if (t == 0) {
      ic[k * NK + 0] = q0; ic[k * NK + 1] = q1; ic[k * NK + 2] = q2;
      ic[k * NK + 3] = q3; ic[k * NK + 4] = q4;
    }
  }
  __syncthreads();
  if (t == 0) {
    double M[NK * NK], b[NK], z[NK];
    for (int i = 0; i < NK * NK; i++) M[i] = ic[i];
    for (int i = 0; i < NK; i++) b[i] = 1.0;
    for (int c = 0; c < NK; c++) {  // GE with partial pivoting: S z = 1
      int pr = c;
      double mb = fabs(M[c * NK + c]);
      for (int r = c + 1; r < NK; r++) {
        double a = fabs(M[r * NK + c]);
        if (a > mb) { mb = a; pr = r; }
      }
      if (pr != c) {
        for (int cc = 0; cc < NK; cc++) {
          double tmp = M[c * NK + cc]; M[c * NK + cc] = M[pr * NK + cc]; M[pr * NK + cc] = tmp;
        }
        double tb = b[c]; b[c] = b[pr]; b[pr] = tb;
      }
      double piv = M[c * NK + c];
      for (int r = c + 1; r < NK; r++) {
        double f = M[r * NK + c] / piv;
        for (int cc = c; cc < NK; cc++) M[r * NK + cc] -= f * M[c * NK + cc];
        b[r] -= f * b[c];
      }
    }
    for (int r = NK - 1; r >= 0; r--) {
      double acc = b[r];
      for (int cc = r + 1; cc < NK; cc++) acc -= M[r * NK + cc] * z[cc];
      z[r] = acc / M[r * NK + r];
    }
    double ssum = z[0] + z[1] + z[2] + z[3] + z[4];
    for (int k = 0; k < NK; k++) w_inter[s * NK + k] = z[k] / ssum;
  }
}

__global__ __launch_bounds__(256) void k_final(const double* __restrict__ walloc, const double* __restrict__ w_inter,
                                               const int* __restrict__ ixs, float* __restrict__ out) {
  int gid = blockIdx.x * 256 + threadIdx.x;
  if (gid >= NS * NA) return;
  int s = gid >> 10;
  out[gid] = (float)(walloc[gid] * w_inter[s * NK + ixs[gid]]);
}

// ---------------- launch ----------------
extern "C" void kernel_launch(void* const* d_in, const int* in_sizes, int n_in,
                              void* d_out, int out_size, void* d_ws, size_t ws_size,
                              hipStream_t stream) {
  const float* cov = (const float*)d_in[0];
  float* out = (float*)d_out;
  char* ws = (char*)d_ws;
  size_t o = 0;
  auto alloc = [&](size_t bytes) {
    size_t cur = o;
    o += (bytes + 255) & ~(size_t)255;
    return cur;
  };
  // total ws usage < 1.5 MB — safe under any ws_size
  double* C = (double*)(ws + alloc((size_t)NS * NK * NA * 8));
  double* y2 = (double*)(ws + alloc((size_t)NS * NK * NA * 8));
  double* rstd = (double*)(ws + alloc((size_t)NS * NA * 8));
  double* xn = (double*)(ws + alloc((size_t)NS * NA * 8));
  double* mind = (double*)(ws + alloc((size_t)NS * NA * 8));
  double* walloc = (double*)(ws + alloc((size_t)NS * NA * 8));
  int* ixs = (int*)(ws + alloc((size_t)NS * NA * 4));
  int* g = (int*)(ws + alloc((size_t)NS * NA * 4));
  int* cnt = (int*)(ws + alloc((size_t)NS * NK * 4));
  int* off5 = (int*)(ws + alloc((size_t)NS * NK * 4));
  int* conv = (int*)(ws + alloc((size_t)NS * 4));
  double* pot = (double*)(ws + alloc((size_t)NS * 8));
  double* w_inter = (double*)(ws + alloc((size_t)NS * NK * 8));
  (void)ws_size; (void)in_sizes; (void)n_in; (void)out_size;

  InitIdx ii;
  compute_init_indices(ii);  // data-independent, identical every call

  k_rstd<<<32, 256, 0, stream>>>(cov, rstd);
  k_xn<<<512, 256, 0, stream>>>(cov, rstd, xn);
  k_centers_init<<<40, 256, 0, stream>>>(cov, rstd, C, ii);
  k_state_init<<<1, 64, 0, stream>>>(pot, conv);
  for (int it = 0; it < MAXIT; it++) {
    k_assign<<<512, 256, 0, stream>>>(cov, rstd, xn, C, conv, ixs, mind);
    k_update<<<40, 256, 0, stream>>>(cov, rstd, ixs, mind, C, pot, conv);
  }
  k_members<<<8, 256, 0, stream>>>(ixs, g, cnt, off5);
  k_cg<<<40, 256, 0, stream>>>(cov, g, cnt, off5, walloc);
  k_intery<<<160, 256, 0, stream>>>(cov, walloc, g, cnt, off5, y2);
  k_icov<<<8, 256, 0, stream>>>(y2, walloc, ixs, w_inter);
  k_final<<<32, 256, 0, stream>>>(walloc, w_inter, ixs, out);
}

// Round 5
// 1839.486 us; speedup vs baseline: 2.9429x; 2.9429x over previous
//
#include <hip/hip_runtime.h>
#include <stdint.h>
#include <math.h>
#include <algorithm>

#define NS 8
#define NA 1024
#define NK 5
#define MAXIT 30
#define TOLER 1e-5

// ---------------- host-side threefry-2x32 (JAX-compatible) ----------------
static inline void tf2x32(uint32_t k0, uint32_t k1, uint32_t c0, uint32_t c1,
                          uint32_t& o0, uint32_t& o1) {
  uint32_t ks2 = k0 ^ k1 ^ 0x1BD11BDAu;
  uint32_t x0 = c0 + k0, x1 = c1 + k1;
  auto rot = [](uint32_t x, int r) { return (x << r) | (x >> (32 - r)); };
  auto R4 = [&](int r0, int r1, int r2, int r3) {
    x0 += x1; x1 = rot(x1, r0); x1 ^= x0;
    x0 += x1; x1 = rot(x1, r1); x1 ^= x0;
    x0 += x1; x1 = rot(x1, r2); x1 ^= x0;
    x0 += x1; x1 = rot(x1, r3); x1 ^= x0;
  };
  R4(13, 15, 26, 6);  x0 += k1;  x1 += ks2 + 1u;
  R4(17, 29, 16, 24); x0 += ks2; x1 += k0 + 2u;
  R4(13, 15, 26, 6);  x0 += k0;  x1 += k1 + 3u;
  R4(17, 29, 16, 24); x0 += k1;  x1 += ks2 + 4u;
  R4(13, 15, 26, 6);  x0 += ks2; x1 += k0 + 5u;
  o0 = x0; o1 = x1;
}

struct InitIdx { int v[NS * NK]; };

// jax_threefry_partitionable=True semantics (verified R3: PASS):
//   split(key,n):  keys[s] = tf(key, (0,s));  bits(key,(n,)): o0^o1 of tf(key,(0,i))
//   choice(1024,(5,),replace=False): subkey = split(key)[1]; argsort_stable(bits)[:5]
static void compute_init_indices(InitIdx& out) {
  const uint32_t rk0 = 0, rk1 = 42;
  for (int s = 0; s < NS; s++) {
    uint32_t k0, k1;
    tf2x32(rk0, rk1, 0u, (uint32_t)s, k0, k1);
    uint32_t sk0, sk1;
    tf2x32(k0, k1, 0u, 1u, sk0, sk1);
    uint32_t bits[NA];
    for (int i = 0; i < NA; i++) {
      uint32_t b0, b1;
      tf2x32(sk0, sk1, 0u, (uint32_t)i, b0, b1);
      bits[i] = b0 ^ b1;
    }
    int idx[NA];
    for (int i = 0; i < NA; i++) idx[i] = i;
    std::stable_sort(idx, idx + NA, [&](int x, int y) { return bits[x] < bits[y]; });
    for (int c = 0; c < NK; c++) out.v[s * NK + c] = idx[c];
  }
}

// ---------------- device helpers ----------------
__device__ __forceinline__ double wave_reduce64(double v) {
#pragma unroll
  for (int m = 32; m > 0; m >>= 1) v += __shfl_xor(v, m, 64);
  return v;
}

// 1024-thread block sum: 2 barriers, deterministic fixed order.
__device__ __forceinline__ double blk_sum_1024(double v, double* red16) {
  double w = wave_reduce64(v);
  if ((threadIdx.x & 63) == 0) red16[threadIdx.x >> 6] = w;
  __syncthreads();
  double tot = 0.0;
#pragma unroll
  for (int i = 0; i < 16; i++) tot += red16[i];
  __syncthreads();
  return tot;
}

// 256-thread block sum: 2 barriers, deterministic.
__device__ __forceinline__ double blk_sum_256(double v, double* red4) {
  double w = wave_reduce64(v);
  if ((threadIdx.x & 63) == 0) red4[threadIdx.x >> 6] = w;
  __syncthreads();
  double tot = red4[0] + red4[1] + red4[2] + red4[3];
  __syncthreads();
  return tot;
}

// ---------------- kernels (f64 state; cov stays f32 as given) ----------------
__global__ __launch_bounds__(256) void k_rstd(const float* __restrict__ cov, double* __restrict__ rstd) {
  int gid = blockIdx.x * 256 + threadIdx.x;
  if (gid >= NS * NA) return;
  int s = gid >> 10, a = gid & 1023;
  double d = (double)cov[(size_t)s * NA * NA + (size_t)a * NA + a];
  rstd[gid] = 1.0 / sqrt(d);
}

__global__ __launch_bounds__(256) void k_xn(const float* __restrict__ cov, const double* __restrict__ rstd,
                                            double* __restrict__ xn) {
  int w = blockIdx.x;  // 512 = 8 samples x 64 blocks x 16 rows
  int s = w >> 6;
  __shared__ double rsh[NA];
  for (int j = threadIdx.x; j < NA; j += 256) rsh[j] = rstd[s * NA + j];
  __syncthreads();
  int lane = threadIdx.x & 63, wave = threadIdx.x >> 6;
  const float* covS = cov + (size_t)s * NA * NA;
  for (int q = 0; q < 4; q++) {
    int i = (w & 63) * 16 + wave * 4 + q;
    const float* row = covS + (size_t)i * NA;
    double acc = 0.0;
    for (int j = lane; j < NA; j += 64) {
      double v = (double)row[j] * rsh[j];
      acc += v * v;
    }
    acc = wave_reduce64(acc);
    if (lane == 0) {
      double ri = rsh[i];
      xn[s * NA + i] = acc * ri * ri;
    }
  }
}

__global__ __launch_bounds__(256) void k_centers_init(const float* __restrict__ cov, const double* __restrict__ rstd,
                                                      double* __restrict__ C, InitIdx ii) {
  int w = blockIdx.x;  // 40
  int s = w / NK, k = w % NK;
  int idx = ii.v[s * NK + k];
  const float* row = cov + (size_t)s * NA * NA + (size_t)idx * NA;
  const double* rs = rstd + s * NA;
  double ri = rs[idx];
  for (int j = threadIdx.x; j < NA; j += 256)
    C[((size_t)s * NK + k) * NA + j] = (double)row[j] * ri * rs[j];
}

__global__ void k_state_init(double* pot, int* conv) {
  int t = threadIdx.x;
  if (t < NS) { pot[t] = INFINITY; conv[t] = 0; }
}

// 256 blocks x 1024 threads: 32 blocks/sample, 32 rows/block, 2 rows/wave.
__global__ __launch_bounds__(1024) void k_assign(const float* __restrict__ cov, const double* __restrict__ rstd,
                                                 const double* __restrict__ xn, const double* __restrict__ C,
                                                 const int* __restrict__ conv, int* __restrict__ ixs,
                                                 double* __restrict__ mind) {
  int w = blockIdx.x;
  int s = w >> 5, rblk = w & 31;
  if (conv[s]) return;
  __shared__ double Cs[NK][NA];  // rstd_j-scaled centers, 40 KB
  __shared__ double red16[16];
  int t = threadIdx.x, lane = t & 63, wid = t >> 6;
  // stage: one j per thread
  double rj = rstd[s * NA + t];
  double sq[NK];
#pragma unroll
  for (int k = 0; k < NK; k++) {
    double c = C[((size_t)s * NK + k) * NA + t];
    Cs[k][t] = c * rj;
    sq[k] = c * c;
  }
  double cn[NK];
#pragma unroll
  for (int k = 0; k < NK; k++) cn[k] = blk_sum_1024(sq[k], red16);  // also orders Cs writes
  const float* covS = cov + (size_t)s * NA * NA;
#pragma unroll
  for (int rr2 = 0; rr2 < 2; rr2++) {
    int i = rblk * 32 + wid * 2 + rr2;
    const float* row = covS + (size_t)i * NA;
    double xi = xn[s * NA + i];          // hoisted: overlaps with dot latency
    double ri = rstd[s * NA + i];
    double a0 = 0, a1 = 0, a2 = 0, a3 = 0, a4 = 0;
#pragma unroll
    for (int c = 0; c < 16; c++) {
      int j = lane + (c << 6);
      double cv = (double)row[j];
      a0 += cv * Cs[0][j];
      a1 += cv * Cs[1][j];
      a2 += cv * Cs[2][j];
      a3 += cv * Cs[3][j];
      a4 += cv * Cs[4][j];
    }
    a0 = wave_reduce64(a0); a1 = wave_reduce64(a1); a2 = wave_reduce64(a2);
    a3 = wave_reduce64(a3); a4 = wave_reduce64(a4);
    if (lane == 0) {
      double dots[5] = {a0, a1, a2, a3, a4};
      double best = INFINITY;
      int bk = 0;
#pragma unroll
      for (int k = 0; k < NK; k++) {
        double d = xi + cn[k] - 2.0 * ri * dots[k];
        if (d < 0.0) d = 0.0;
        if (d < best) { best = d; bk = k; }  // strict < : first-min like jnp.argmin
      }
      ixs[s * NA + i] = bk;
      mind[s * NA + i] = best;
    }
  }
}

// 264 blocks x 256 thr: 256 C-partial blocks (s x ioct x seg) + 8 pot blocks.
// C-partial blocks are UNGATED (idempotent once frozen); only pot blocks touch conv.
__global__ __launch_bounds__(256) void k_update_part(const float* __restrict__ cov, const double* __restrict__ rstd,
                                                     const int* __restrict__ ixs, const double* __restrict__ mind,
                                                     double* __restrict__ pU, double* __restrict__ pot,
                                                     int* __restrict__ conv) {
  int w = blockIdx.x, t = threadIdx.x;
  __shared__ double red4[4];
  if (w < 256) {
    int s = w >> 5, ioct = (w >> 2) & 7, seg = w & 3;
    __shared__ int ixsh[128];
    __shared__ double rssh[128];
    if (t < 128) {
      int i = ioct * 128 + t;
      ixsh[t] = ixs[s * NA + i];
      rssh[t] = rstd[s * NA + i];
    }
    __syncthreads();
    int j = seg * 256 + t;
    const float* colS = cov + (size_t)s * NA * NA + j;
    double a0 = 0, a1 = 0, a2 = 0, a3 = 0, a4 = 0;
    for (int ii = 0; ii < 128; ii++) {  // ascending i: deterministic
      int i = ioct * 128 + ii;
      double v = rssh[ii] * (double)colS[(size_t)i * NA];
      int kk = ixsh[ii];
      a0 += (kk == 0) ? v : 0.0;
      a1 += (kk == 1) ? v : 0.0;
      a2 += (kk == 2) ? v : 0.0;
      a3 += (kk == 3) ? v : 0.0;
      a4 += (kk == 4) ? v : 0.0;
    }
    double* p = pU + ((size_t)w * NK) * 256;
    p[0 * 256 + t] = a0; p[1 * 256 + t] = a1; p[2 * 256 + t] = a2;
    p[3 * 256 + t] = a3; p[4 * 256 + t] = a4;
  } else {
    int s = w - 256;
    if (conv[s]) return;
    double v = mind[s * NA + t] + mind[s * NA + 256 + t] +
               mind[s * NA + 512 + t] + mind[s * NA + 768 + t];
    double p = blk_sum_256(v, red4);
    if (t == 0) {
      double prev = pot[s];
      pot[s] = p;
      if (!(fabs(p - prev) >= TOLER)) conv[s] = 1;  // freeze sample (while-cond fails)
    }
  }
}

// 32 blocks (s x seg): fixed-order combine of 8 ioct partials + counts; write C.
__global__ __launch_bounds__(256) void k_update_fin(const double* __restrict__ pU, const double* __restrict__ rstd,
                                                    const int* __restrict__ ixs, double* __restrict__ C) {
  int w = blockIdx.x, t = threadIdx.x;
  int s = w >> 2, seg = w & 3;
  __shared__ double red4[4];
  // counts from ixs (exact, deterministic)
  double lc[NK] = {0, 0, 0, 0, 0};
#pragma unroll
  for (int q = 0; q < 4; q++) {
    int c = ixs[s * NA + q * 256 + t];
#pragma unroll
    for (int k = 0; k < NK; k++) lc[k] += (c == k) ? 1.0 : 0.0;
  }
  double cnt[NK];
#pragma unroll
  for (int k = 0; k < NK; k++) cnt[k] = blk_sum_256(lc[k], red4);
  int j = seg * 256 + t;
  double rj = rstd[s * NA + j];
  double* CS = C + (size_t)s * NK * NA;
#pragma unroll
  for (int k = 0; k < NK; k++) {
    double acc = 0.0;
#pragma unroll
    for (int g = 0; g < 8; g++) {  // ascending ioct: deterministic
      int blk = (s << 5) | (g << 2) | seg;
      acc += pU[((size_t)blk * NK + k) * 256 + t];
    }
    if (cnt[k] > 0.0) CS[(size_t)k * NA + j] = acc * rj / cnt[k];
    // empty cluster: keep previous center (matches jnp.where(counts>0,...))
  }
}

__global__ __launch_bounds__(256) void k_members(const int* __restrict__ ixs, int* __restrict__ g,
                                                 int* __restrict__ cnt, int* __restrict__ off5) {
  int s = blockIdx.x, t = threadIdx.x;
  __shared__ int sc[NK][256];
  __shared__ int base[NK];
  const int* ix = ixs + s * NA;
  int my[4];
  int lc[NK] = {0, 0, 0, 0, 0};
#pragma unroll
  for (int q = 0; q < 4; q++) { my[q] = ix[t * 4 + q]; lc[my[q]]++; }
#pragma unroll
  for (int k = 0; k < NK; k++) sc[k][t] = lc[k];
  __syncthreads();
  for (int off = 1; off < 256; off <<= 1) {
    int v[NK];
#pragma unroll
    for (int k = 0; k < NK; k++) v[k] = (t >= off) ? sc[k][t - off] : 0;
    __syncthreads();
#pragma unroll
    for (int k = 0; k < NK; k++) sc[k][t] += v[k];
    __syncthreads();
  }
  if (t == 0) {
    int b = 0;
    for (int k = 0; k < NK; k++) {
      int tot = sc[k][255];
      base[k] = b;
      cnt[s * NK + k] = tot;
      off5[s * NK + k] = b;
      b += tot;
    }
  }
  __syncthreads();
  int pos[NK];
#pragma unroll
  for (int k = 0; k < NK; k++) pos[k] = base[k] + sc[k][t] - lc[k];
#pragma unroll
  for (int q = 0; q < 4; q++) {
    int k = my[q];
    int p = pos[k]++;
    g[s * NA + p] = t * 4 + q;  // stable: ascending asset index within cluster
  }
}

// f64 CG on the COVARIANCE block Sigma_cc x = 1 (no rstd scaling! R4's bug was
// solving the correlation system). 1024 threads, full-row coalesced masked matvec.
__global__ __launch_bounds__(1024) void k_cg(const float* __restrict__ cov,
                                             const int* __restrict__ g, const int* __restrict__ cnt,
                                             const int* __restrict__ off5, double* __restrict__ walloc) {
  int w = blockIdx.x;  // 40
  int s = w / NK, k = w % NK;
  int n = cnt[s * NK + k];
  if (n == 0) return;
  int off = off5[s * NK + k];
  const float* covS = cov + (size_t)s * NA * NA;
  __shared__ double pfull[NA];                 // p scattered to original indices, zero outside cluster
  __shared__ double xv[NA], rv[NA], pv[NA], ap[NA];
  __shared__ int gs[NA];
  __shared__ double red16[16];
  int t = threadIdx.x, lane = t & 63, wid = t >> 6;
  if (t < n) {
    gs[t] = g[s * NA + off + t];
    xv[t] = 0.0; rv[t] = 1.0; pv[t] = 1.0;
  }
  double rr = (double)n;
  __syncthreads();
  for (int iter = 0; iter < 150; iter++) {
    pfull[t] = 0.0;
    __syncthreads();
    if (t < n) pfull[gs[t]] = pv[t];
    __syncthreads();
    for (int i = wid; i < n; i += 16) {
      const float* row = covS + (size_t)gs[i] * NA;
      double acc = 0.0;
#pragma unroll
      for (int c = 0; c < 16; c++) {
        int j = lane + (c << 6);
        acc += (double)row[j] * pfull[j];   // pfull masked -> exact cluster dot
      }
      acc = wave_reduce64(acc);
      if (lane == 0) ap[i] = acc;
    }
    __syncthreads();
    double pp = (t < n) ? pv[t] * ap[t] : 0.0;
    double pap = blk_sum_1024(pp, red16);
    double alpha = rr / pap;
    double rp = 0.0;
    if (t < n) {
      xv[t] += alpha * pv[t];
      double rn = rv[t] - alpha * ap[t];
      rv[t] = rn;
      rp = rn * rn;
    }
    double rrn = blk_sum_1024(rp, red16);
    if (rrn < 1e-20 * (double)n) break;        // rel resid 1e-10; uniform branch
    double beta = rrn / rr;
    rr = rrn;
    if (t < n) pv[t] = rv[t] + beta * pv[t];
    __syncthreads();
  }
  double dp = (t < n) ? xv[t] : 0.0;
  double denom = blk_sum_1024(dp, red16);
  if (t < n) walloc[s * NA + gs[t]] = xv[t] / denom;
}

// y2[s][k][j] = sum_{i in cluster k} w_i * cov[i][j]  (j in ORIGINAL order, coalesced)
__global__ __launch_bounds__(256) void k_intery(const float* __restrict__ cov, const double* __restrict__ walloc,
                                                const int* __restrict__ g, const int* __restrict__ cnt,
                                                const int* __restrict__ off5, double* __restrict__ y2) {
  int w = blockIdx.x;  // 160 = 8 x 5 x 4 segs
  int s = w / 20, rem = w % 20, k = rem / 4, seg = rem % 4;
  int n = cnt[s * NK + k], off = off5[s * NK + k];
  int t = threadIdx.x;
  __shared__ int gsl[NA];
  __shared__ double wl[NA];
  for (int i = t; i < n; i += 256) {
    int a = g[s * NA + off + i];
    gsl[i] = a;
    wl[i] = walloc[s * NA + a];
  }
  __syncthreads();
  int j = seg * 256 + t;
  const float* covS = cov + (size_t)s * NA * NA;
  double acc = 0.0;
  for (int i = 0; i < n; i++) acc += wl[i] * (double)covS[(size_t)gsl[i] * NA + j];
  y2[((size_t)s * NK + k) * NA + j] = acc;
}

__global__ __launch_bounds__(256) void k_icov(const double* __restrict__ y2, const double* __restrict__ walloc,
                                              const int* __restrict__ ixs, double* __restrict__ w_inter) {
  int s = blockIdx.x, t = threadIdx.x;
  __shared__ double red4[4];
  __shared__ double ic[NK * NK];
  for (int k = 0; k < NK; k++) {
    double p0 = 0, p1 = 0, p2 = 0, p3 = 0, p4 = 0;
    for (int j = t; j < NA; j += 256) {
      double v = y2[((size_t)s * NK + k) * NA + j] * walloc[s * NA + j];
      int c = ixs[s * NA + j];
      p0 += (c == 0) ? v : 0.0;
      p1 += (c == 1) ? v : 0.0;
      p2 += (c == 2) ? v : 0.0;
      p3 += (c == 3) ? v : 0.0;
      p4 += (c == 4) ? v : 0.0;
    }
    double q0 = blk_sum_256(p0, red4);
    double q1 = blk_sum_256(p1, red4);
    double q2 = blk_sum_256(p2, red4);
    double q3 = blk_sum_256(p3, red4);
    double q4 = blk_sum_256(p4, red4);
    if (t == 0) {
      ic[k * NK + 0] = q0; ic[k * NK + 1] = q1; ic[k * NK + 2] = q2;
      ic[k * NK + 3] = q3; ic[k * NK + 4] = q4;
    }
  }
  __syncthreads();
  if (t == 0) {
    double M[NK * NK], b[NK], z[NK];
    for (int i = 0; i < NK * NK; i++) M[i] = ic[i];
    for (int i = 0; i < NK; i++) b[i] = 1.0;
    for (int c = 0; c < NK; c++) {  // GE with partial pivoting: S z = 1
      int pr = c;
      double mb = fabs(M[c * NK + c]);
      for (int r = c + 1; r < NK; r++) {
        double a = fabs(M[r * NK + c]);
        if (a > mb) { mb = a; pr = r; }
      }
      if (pr != c) {
        for (int cc = 0; cc < NK; cc++) {
          double tmp = M[c * NK + cc]; M[c * NK + cc] = M[pr * NK + cc]; M[pr * NK + cc] = tmp;
        }
        double tb = b[c]; b[c] = b[pr]; b[pr] = tb;
      }
      double piv = M[c * NK + c];
      for (int r = c + 1; r < NK; r++) {
        double f = M[r * NK + c] / piv;
        for (int cc = c; cc < NK; cc++) M[r * NK + cc] -= f * M[c * NK + cc];
        b[r] -= f * b[c];
      }
    }
    for (int r = NK - 1; r >= 0; r--) {
      double acc = b[r];
      for (int cc = r + 1; cc < NK; cc++) acc -= M[r * NK + cc] * z[cc];
      z[r] = acc / M[r * NK + r];
    }
    double ssum = z[0] + z[1] + z[2] + z[3] + z[4];
    for (int k = 0; k < NK; k++) w_inter[s * NK + k] = z[k] / ssum;
  }
}

__global__ __launch_bounds__(256) void k_final(const double* __restrict__ walloc, const double* __restrict__ w_inter,
                                               const int* __restrict__ ixs, float* __restrict__ out) {
  int gid = blockIdx.x * 256 + threadIdx.x;
  if (gid >= NS * NA) return;
  int s = gid >> 10;
  out[gid] = (float)(walloc[gid] * w_inter[s * NK + ixs[gid]]);
}

// ---------------- launch ----------------
extern "C" void kernel_launch(void* const* d_in, const int* in_sizes, int n_in,
                              void* d_out, int out_size, void* d_ws, size_t ws_size,
                              hipStream_t stream) {
  const float* cov = (const float*)d_in[0];
  float* out = (float*)d_out;
  char* ws = (char*)d_ws;
  size_t o = 0;
  auto alloc = [&](size_t bytes) {
    size_t cur = o;
    o += (bytes + 255) & ~(size_t)255;
    return cur;
  };
  // total ws usage ~4 MB
  double* C = (double*)(ws + alloc((size_t)NS * NK * NA * 8));
  double* y2 = (double*)(ws + alloc((size_t)NS * NK * NA * 8));
  double* pU = (double*)(ws + alloc((size_t)256 * NK * 256 * 8));  // update partials, 2.6 MB
  double* rstd = (double*)(ws + alloc((size_t)NS * NA * 8));
  double* xn = (double*)(ws + alloc((size_t)NS * NA * 8));
  double* mind = (double*)(ws + alloc((size_t)NS * NA * 8));
  double* walloc = (double*)(ws + alloc((size_t)NS * NA * 8));
  int* ixs = (int*)(ws + alloc((size_t)NS * NA * 4));
  int* g = (int*)(ws + alloc((size_t)NS * NA * 4));
  int* cnt = (int*)(ws + alloc((size_t)NS * NK * 4));
  int* off5 = (int*)(ws + alloc((size_t)NS * NK * 4));
  int* conv = (int*)(ws + alloc((size_t)NS * 4));
  double* pot = (double*)(ws + alloc((size_t)NS * 8));
  double* w_inter = (double*)(ws + alloc((size_t)NS * NK * 8));
  (void)ws_size; (void)in_sizes; (void)n_in; (void)out_size;

  InitIdx ii;
  compute_init_indices(ii);  // data-independent, identical every call

  k_rstd<<<32, 256, 0, stream>>>(cov, rstd);
  k_xn<<<512, 256, 0, stream>>>(cov, rstd, xn);
  k_centers_init<<<40, 256, 0, stream>>>(cov, rstd, C, ii);
  k_state_init<<<1, 64, 0, stream>>>(pot, conv);
  for (int it = 0; it < MAXIT; it++) {
    k_assign<<<256, 1024, 0, stream>>>(cov, rstd, xn, C, conv, ixs, mind);
    k_update_part<<<264, 256, 0, stream>>>(cov, rstd, ixs, mind, pU, pot, conv);
    k_update_fin<<<32, 256, 0, stream>>>(pU, rstd, ixs, C);
  }
  k_members<<<8, 256, 0, stream>>>(ixs, g, cnt, off5);
  k_cg<<<40, 1024, 0, stream>>>(cov, g, cnt, off5, walloc);
  k_intery<<<160, 256, 0, stream>>>(cov, walloc, g, cnt, off5, y2);
  k_icov<<<8, 256, 0, stream>>>(y2, walloc, ixs, w_inter);
  k_final<<<32, 256, 0, stream>>>(walloc, w_inter, ixs, out);
}